// Round 1
// 450.187 us; speedup vs baseline: 1.1477x; 1.1477x over previous
//
#include <hip/hip_runtime.h>
#include <hip/hip_bf16.h>

// SpookyNet Performer-style attention, N=262144, d=128, m=256, f32 in/out.
// out = (Qp·Kp) * V / (Qp·sum_n Kp + 1e-8), Qp/Kp = (exp(U - h - max) + 1e-4)/16
// U matmuls via f16 MFMA (16x16x32), everything else f32.
//
// This version: omega stored in MFMA-fragment-major order
//   omt[((t*4+ks)*64 + lane)*8 + j] = omega[ks*32 + (lane>>4)*8 + j][t*16 + (lane&15)]
// so (a) global->LDS staging is a linear 64KB copy (coalesced float4 loads,
// conflict-free lane-contiguous ds_write_b128), one phase, ONE barrier, and
// (b) every B-fragment ds_read_b128 is lane-contiguous 1KB/wave -> zero bank
// conflicts (old padded layout was ~8-way conflicted, 4.19M conflicts/dispatch).

typedef _Float16 f16x8 __attribute__((ext_vector_type(8)));
typedef float f32x4 __attribute__((ext_vector_type(4)));

#define D_QK 128
#define M_F  256
#define OMT_HALVES 32768   // 16 t * 4 ks * 64 lanes * 8 halves = 64 KB

constexpr float D4      = 0.29730177875068026f;   // 128^-0.25
constexpr float H_SCALE = 0.044194173824159216f;  // 1/(2*sqrt(128))

__device__ __forceinline__ unsigned f2key(float f) {
  unsigned b = __float_as_uint(f);
  return (b & 0x80000000u) ? ~b : (b | 0x80000000u);   // monotone total order on floats
}
__device__ __forceinline__ float key2f(unsigned k) {
  return (k & 0x80000000u) ? __uint_as_float(k & 0x7fffffffu) : __uint_as_float(~k);
}

__device__ __forceinline__ f32x4 mfma16(f16x8 a, f16x8 b, f32x4 c) {
  return __builtin_amdgcn_mfma_f32_16x16x32_f16(a, b, c, 0, 0, 0);
}

// Load one A-fragment (8 consecutive f32 of row), scale to f16, accumulate sum-of-squares.
__device__ __forceinline__ void load_frag(const float* __restrict__ row, int ks, int q,
                                          f16x8& a, float& h) {
  const float4* p = (const float4*)(row + ks * 32 + q * 8);
  float4 x0 = p[0], x1 = p[1];
  h += x0.x*x0.x + x0.y*x0.y + x0.z*x0.z + x0.w*x0.w
     + x1.x*x1.x + x1.y*x1.y + x1.z*x1.z + x1.w*x1.w;
  a[0] = (_Float16)(x0.x * D4); a[1] = (_Float16)(x0.y * D4);
  a[2] = (_Float16)(x0.z * D4); a[3] = (_Float16)(x0.w * D4);
  a[4] = (_Float16)(x1.x * D4); a[5] = (_Float16)(x1.y * D4);
  a[6] = (_Float16)(x1.z * D4); a[7] = (_Float16)(x1.w * D4);
}

// B-fragment LDS read: lane-contiguous, conflict-free.
__device__ __forceinline__ f16x8 bfrag(const _Float16* om_lds, int t, int ks, int lane) {
  return *(const f16x8*)&om_lds[(((t << 2) | ks) << 9) + (lane << 3)];
}

// ---------------------------------------------------------------------------
// k_prep: omega (d,m) f32 -> omt fragment-major f16; init S=0, Mkey=0.
extern "C" __global__ void k_prep(const float* __restrict__ om, _Float16* __restrict__ omt,
                                  float* __restrict__ S, unsigned* __restrict__ Mkey) {
  int i = blockIdx.x * 256 + threadIdx.x;           // grid = 128 blocks
  if (i < OMT_HALVES) {
    int t = i >> 11, ks = (i >> 9) & 3, l = (i >> 3) & 63, j = i & 7;
    int d = ks * 32 + ((l >> 4) << 3) + j;
    int m = t * 16 + (l & 15);
    omt[i] = (_Float16)om[d * M_F + m];
  }
  if (blockIdx.x == 0) {
    S[threadIdx.x] = 0.f;
    if (threadIdx.x == 0) *Mkey = 0u;
  }
}

// ---------------------------------------------------------------------------
// k_kstats: per 64-row block of K: U_K = (K*D4)@omega, block max Lb of raw U,
// column sums P_b[m] = sum_rows exp(U - h - Lb). atomicMax global max key.
__global__ __launch_bounds__(256, 2) void k_kstats(
    const float* __restrict__ K, const _Float16* __restrict__ omt,
    float* __restrict__ Lout, float* __restrict__ Pout, unsigned* __restrict__ Mkey) {
  __shared__ __align__(16) _Float16 om_lds[OMT_HALVES];   // 64 KB
  __shared__ float P_lds[4][256];
  __shared__ float red_lds[4];
  int tid = threadIdx.x;
  int w = tid >> 6, lane = tid & 63, q = lane >> 4, c = lane & 15;
  int rb = blockIdx.x * 64 + w * 16;

  // Issue the 64KB omega staging loads first (linear copy, L2-resident).
  const float4* osrc = (const float4*)omt;
  float4 st[16];
#pragma unroll
  for (int i = 0; i < 16; ++i) st[i] = osrc[tid + i * 256];

  // Overlap K loads + h compute under the staging latency.
  const float* krow = K + (size_t)(rb + c) * D_QK;
  f16x8 ak[4];
  float hk = 0.f;
#pragma unroll
  for (int ks = 0; ks < 4; ++ks) load_frag(krow, ks, q, ak[ks], hk);
  hk += __shfl_xor(hk, 16, 64);
  hk += __shfl_xor(hk, 32, 64);
  hk *= H_SCALE;                             // h for row rb+c, in every lane with this c

  float4* odst = (float4*)om_lds;
#pragma unroll
  for (int i = 0; i < 16; ++i) odst[tid + i * 256] = st[i];   // conflict-free b128 writes

  const f32x4 zero = {0.f, 0.f, 0.f, 0.f};
  f32x4 cc[16];
#pragma unroll
  for (int t = 0; t < 16; ++t) cc[t] = zero;
  __syncthreads();                           // the ONE barrier

#pragma unroll
  for (int t = 0; t < 16; ++t) {
#pragma unroll
    for (int ks = 0; ks < 4; ++ks) {
      f16x8 b = bfrag(om_lds, t, ks, lane);
      cc[t] = mfma16(ak[ks], b, cc[t]);
    }
  }

  // block max over raw U
  float mx = cc[0][0];
#pragma unroll
  for (int t = 0; t < 16; ++t)
    mx = fmaxf(mx, fmaxf(fmaxf(cc[t][0], cc[t][1]), fmaxf(cc[t][2], cc[t][3])));
#pragma unroll
  for (int m = 1; m <= 32; m <<= 1) mx = fmaxf(mx, __shfl_xor(mx, m, 64));
  if (lane == 0) red_lds[w] = mx;
  __syncthreads();
  float Lb = fmaxf(fmaxf(red_lds[0], red_lds[1]), fmaxf(red_lds[2], red_lds[3]));

  // h for the C-layout rows (row = q*4+r)
  float hr[4];
#pragma unroll
  for (int r = 0; r < 4; ++r) hr[r] = __shfl(hk, q * 4 + r, 64);

#pragma unroll
  for (int t = 0; t < 16; ++t) {
    float s = __expf(cc[t][0] - hr[0] - Lb) + __expf(cc[t][1] - hr[1] - Lb)
            + __expf(cc[t][2] - hr[2] - Lb) + __expf(cc[t][3] - hr[3] - Lb);
    s += __shfl_xor(s, 16, 64);
    s += __shfl_xor(s, 32, 64);            // col sum over this wave's 16 rows
    if (q == 0) P_lds[w][t * 16 + c] = s;
  }
  __syncthreads();
  Pout[(size_t)blockIdx.x * 256 + tid] =
      P_lds[0][tid] + P_lds[1][tid] + P_lds[2][tid] + P_lds[3][tid];
  if (tid == 0) {
    Lout[blockIdx.x] = Lb;
    atomicMax(Mkey, f2key(Lb));
  }
}

// ---------------------------------------------------------------------------
// k_combine: S[m] = sum_b exp(Lb - M) * P_b[m]; write M as float.
extern "C" __global__ void k_combine(const float* __restrict__ Lout, const float* __restrict__ Pout,
                                     const unsigned* __restrict__ Mkey, float* __restrict__ Mout,
                                     float* __restrict__ S) {
  float M = key2f(*Mkey);
  if (blockIdx.x == 0 && threadIdx.x == 0) *Mout = M;
  int b0 = blockIdx.x * 8;                  // grid = nblk/8 = 512 blocks
  float acc = 0.f;
#pragma unroll
  for (int i = 0; i < 8; ++i) {
    int b = b0 + i;
    float f = __expf(Lout[b] - M);
    acc += f * Pout[(size_t)b * 256 + threadIdx.x];
  }
  atomicAdd(&S[threadIdx.x], acc);
}

// ---------------------------------------------------------------------------
// k_main: per 64-row block: U_Q and U_K (B-fragment shared), Qp/Kp, w, norm,
// out = (w/norm) * V.
__global__ __launch_bounds__(256, 2) void k_main(
    const float* __restrict__ Q, const float* __restrict__ K, const float* __restrict__ V,
    const _Float16* __restrict__ omt, const float* __restrict__ Sws,
    const float* __restrict__ Mws, float* __restrict__ out, float epsN) {
  __shared__ __align__(16) _Float16 om_lds[OMT_HALVES];   // 64 KB
  __shared__ float S_lds[256];
  __shared__ float scale_lds[64];
  int tid = threadIdx.x;
  int w = tid >> 6, lane = tid & 63, q = lane >> 4, c = lane & 15;
  int rb = blockIdx.x * 64 + w * 16;

  // Issue the omega staging loads first.
  const float4* osrc = (const float4*)omt;
  float4 st[16];
#pragma unroll
  for (int i = 0; i < 16; ++i) st[i] = osrc[tid + i * 256];

  S_lds[tid] = (Sws[tid] + epsN) * 0.0625f;   // true S (incl. N*eps, /sqrt(m))
  float Mglob = *Mws;

  // Overlap Q/K loads + h compute under the staging latency.
  const float* qrow = Q + (size_t)(rb + c) * D_QK;
  const float* krow = K + (size_t)(rb + c) * D_QK;
  f16x8 aq[4], ak[4];
  float hq = 0.f, hk = 0.f;
#pragma unroll
  for (int ks = 0; ks < 4; ++ks) {
    load_frag(qrow, ks, q, aq[ks], hq);
    load_frag(krow, ks, q, ak[ks], hk);
  }
  hq += __shfl_xor(hq, 16, 64); hq += __shfl_xor(hq, 32, 64); hq *= H_SCALE;
  hk += __shfl_xor(hk, 16, 64); hk += __shfl_xor(hk, 32, 64); hk *= H_SCALE;

  float4* odst = (float4*)om_lds;
#pragma unroll
  for (int i = 0; i < 16; ++i) odst[tid + i * 256] = st[i];

  const f32x4 zero = {0.f, 0.f, 0.f, 0.f};
  f32x4 cq[16], ck[16];
#pragma unroll
  for (int t = 0; t < 16; ++t) { cq[t] = zero; ck[t] = zero; }
  __syncthreads();                           // the ONE barrier before compute

#pragma unroll
  for (int t = 0; t < 16; ++t) {
#pragma unroll
    for (int ks = 0; ks < 4; ++ks) {
      f16x8 b = bfrag(om_lds, t, ks, lane);
      cq[t] = mfma16(aq[ks], b, cq[t]);
      ck[t] = mfma16(ak[ks], b, ck[t]);
    }
  }

  float hqr[4], hkr[4];
#pragma unroll
  for (int r = 0; r < 4; ++r) {
    hqr[r] = __shfl(hq, q * 4 + r, 64);
    hkr[r] = __shfl(hk, q * 4 + r, 64);
  }

#pragma unroll
  for (int r = 0; r < 4; ++r) {
    float mx = cq[0][r];
#pragma unroll
    for (int t = 1; t < 16; ++t) mx = fmaxf(mx, cq[t][r]);
#pragma unroll
    for (int m = 1; m <= 8; m <<= 1) mx = fmaxf(mx, __shfl_xor(mx, m, 64));
    float wsum = 0.f, nsum = 0.f;
#pragma unroll
    for (int t = 0; t < 16; ++t) {
      float qp = __expf(cq[t][r] - hqr[r] - mx) + 1e-4f;      // Qp * 16
      float kp = __expf(ck[t][r] - hkr[r] - Mglob) + 1e-4f;   // Kp * 16
      wsum += qp * kp;
      nsum += qp * S_lds[t * 16 + c];
    }
#pragma unroll
    for (int m = 1; m <= 8; m <<= 1) {
      wsum += __shfl_xor(wsum, m, 64);
      nsum += __shfl_xor(nsum, m, 64);
    }
    if (c == 0)
      scale_lds[w * 16 + q * 4 + r] = (wsum * (1.f / 256.f)) / (nsum * 0.0625f + 1e-8f);
  }
  __syncthreads();

  const float4* vsrc = (const float4*)(V + (size_t)blockIdx.x * 64 * D_QK);
  float4* odst4 = (float4*)(out + (size_t)blockIdx.x * 64 * D_QK);
#pragma unroll
  for (int i = 0; i < 8; ++i) {
    int j = tid + i * 256;                  // 2048 float4 = 64 rows x 128 f32
    float s = scale_lds[j >> 5];
    float4 v = vsrc[j];
    odst4[j] = make_float4(v.x * s, v.y * s, v.z * s, v.w * s);
  }
}

// ---------------------------------------------------------------------------
extern "C" void kernel_launch(void* const* d_in, const int* in_sizes, int n_in,
                              void* d_out, int out_size, void* d_ws, size_t ws_size,
                              hipStream_t stream) {
  const float* Q  = (const float*)d_in[0];
  const float* K  = (const float*)d_in[1];
  const float* V  = (const float*)d_in[2];
  const float* om = (const float*)d_in[3];
  float* out = (float*)d_out;
  int N = in_sizes[0] / D_QK;               // 262144
  int nblk = N / 64;                        // 4096

  // ws layout (bytes): omt[65536] | Lout[nblk*4] | Pout[nblk*256*4] | S[1024] | Mkey | Mout
  char* ws = (char*)d_ws;
  _Float16* omt = (_Float16*)ws;
  size_t off = (size_t)OMT_HALVES * 2;                // 65536
  float* Lout = (float*)(ws + off);   off += (size_t)nblk * 4;
  float* Pout = (float*)(ws + off);   off += (size_t)nblk * 256 * 4;
  float* S    = (float*)(ws + off);   off += 1024;
  unsigned* Mkey = (unsigned*)(ws + off); off += 16;
  float* Mout = (float*)(ws + off);

  hipLaunchKernelGGL(k_prep, dim3((OMT_HALVES + 255) / 256), dim3(256), 0, stream,
                     om, omt, S, Mkey);
  hipLaunchKernelGGL(k_kstats, dim3(nblk), dim3(256), 0, stream, K, omt, Lout, Pout, Mkey);
  hipLaunchKernelGGL(k_combine, dim3(nblk / 8), dim3(256), 0, stream, Lout, Pout, Mkey, Mout, S);
  hipLaunchKernelGGL(k_main, dim3(nblk), dim3(256), 0, stream, Q, K, V, omt, S, Mout, out,
                     (float)N * 1e-4f);
}